// Round 1
// baseline (759.431 us; speedup 1.0000x reference)
//
#include <hip/hip_runtime.h>

#define T_DIM 2048
#define D_DIM 128
#define CT 768
#define LOOKUP 101
#define PADK 50

// ---------------- Kernel 1: spatial mean over 7x7=49 ----------------
// Each block: 256 rows of 49 floats. Coalesced float4 global loads -> LDS,
// then each thread sums one row (stride 49 = odd -> max 2-way bank alias, free).
__global__ __launch_bounds__(256) void mean49_kernel(const float* __restrict__ in,
                                                     float* __restrict__ feats,
                                                     int rowsPerBatch,   // C*T of this input
                                                     int outChanOffset)  // 0 or 256
{
    __shared__ float4 ldsV[3136];                // 256*49/4 float4 = 50176 B
    float* lds = (float*)ldsV;
    const long long blockRow0 = (long long)blockIdx.x * 256;
    const float4* src4 = (const float4*)(in + blockRow0 * 49);

    #pragma unroll
    for (int i = 0; i < 12; ++i)
        ldsV[i * 256 + threadIdx.x] = src4[i * 256 + threadIdx.x];
    if (threadIdx.x < 64)
        ldsV[12 * 256 + threadIdx.x] = src4[12 * 256 + threadIdx.x];
    __syncthreads();

    float s = 0.f;
    #pragma unroll
    for (int i = 0; i < 49; ++i) s += lds[threadIdx.x * 49 + i];
    s *= (1.0f / 49.0f);

    const int r   = (int)blockRow0 + threadIdx.x;      // b*rowsPerBatch + c*T + t
    const int b   = r / rowsPerBatch;                  // power-of-two divide
    const int rem = r - b * rowsPerBatch;              // c*T + t
    feats[(long long)b * (CT * T_DIM) + (long long)outChanOffset * T_DIM + rem] = s;
}

// ---------------- Kernel 2: projection + L2 normalize ----------------
// x[b,t,d] = sum_c feats[b,c,t] * Wp[c,d]; then row-normalize over d.
// Block: 256 threads = 128 d-lanes x 2 t-groups; t-tile = 8.
__global__ __launch_bounds__(256) void proj_norm_kernel(const float* __restrict__ feats,
                                                        const float* __restrict__ Wp,
                                                        float* __restrict__ x)
{
    __shared__ __align__(16) float fTile[CT * 8];    // 24.6 KB
    __shared__ float xTile[8][D_DIM];                // 4 KB
    __shared__ float norms[8];

    const int b  = blockIdx.y;
    const int t0 = blockIdx.x * 8;
    const float* fb = feats + (long long)b * CT * T_DIM;

    // stage feats[b, :, t0:t0+8] : 768 x 8 floats = 1536 float4
    for (int i = threadIdx.x; i < 1536; i += 256) {
        const int c = i >> 1, q = i & 1;
        *(float4*)(&fTile[c * 8 + q * 4]) = *(const float4*)(fb + c * T_DIM + t0 + q * 4);
    }
    __syncthreads();

    const int d = threadIdx.x & 127;
    const int g = threadIdx.x >> 7;    // which 4-t sub-tile
    float a0 = 0.f, a1 = 0.f, a2 = 0.f, a3 = 0.f;
    #pragma unroll 4
    for (int c = 0; c < CT; ++c) {
        const float w = Wp[c * D_DIM + d];
        const float4 f = *(const float4*)(&fTile[c * 8 + g * 4]);
        a0 += w * f.x; a1 += w * f.y; a2 += w * f.z; a3 += w * f.w;
    }
    xTile[g * 4 + 0][d] = a0;
    xTile[g * 4 + 1][d] = a1;
    xTile[g * 4 + 2][d] = a2;
    xTile[g * 4 + 3][d] = a3;
    __syncthreads();

    // norms: wave w reduces rows 2w, 2w+1
    {
        const int wid  = threadIdx.x >> 6;
        const int lane = threadIdx.x & 63;
        #pragma unroll
        for (int tt = 0; tt < 2; ++tt) {
            const int t = wid * 2 + tt;
            float v = xTile[t][lane];
            v = v * v + xTile[t][lane + 64] * xTile[t][lane + 64];
            #pragma unroll
            for (int off = 32; off > 0; off >>= 1) v += __shfl_down(v, off);
            if (lane == 0) norms[t] = v;
        }
    }
    __syncthreads();

    float* xb = x + ((long long)b * T_DIM + t0) * D_DIM;
    #pragma unroll
    for (int i = 0; i < 4; ++i) {
        const int t = g * 4 + i;
        const float n = sqrtf(norms[t]);
        const float sc = 1.0f / fmaxf(n, 1e-12f);
        xb[t * D_DIM + d] = xTile[t][d] * sc;
    }
}

// ---------------- Kernel 3: banded sims + FC + bias + relu ----------------
// band[b,t,k] = dot(x[b,t,:], x[b,t+k-50,:]) (0 if OOB), k in [0,101)
// out[b,t,j] = relu(sum_k band[b,t,k]*fc_w[k,j] + fc_b[j])
// Block: t-tile = 16, stage rows t0-50 .. t0+69 (120 rows incl. scratch tail).
__global__ __launch_bounds__(256) void band_fc_kernel(const float* __restrict__ x,
                                                      const float* __restrict__ fc_w,
                                                      const float* __restrict__ fc_b,
                                                      float* __restrict__ out)
{
    __shared__ float xs[120][D_DIM + 1];   // +1 pad: row-indexed reads conflict-free (61.9 KB)
    __shared__ float band[16][LOOKUP + 3]; // 104 stride (6.7 KB)

    const int b  = blockIdx.y;
    const int t0 = blockIdx.x * 16;
    const float* xb = x + (long long)b * T_DIM * D_DIM;

    // stage 120 rows (rows >=116 are never used by kept results; zero-filled OOB)
    for (int i = threadIdx.x; i < 120 * D_DIM; i += 256) {
        const int r = i >> 7, dd = i & 127;
        const int s = t0 - PADK + r;
        xs[r][dd] = (s >= 0 && s < T_DIM) ? xb[s * D_DIM + dd] : 0.f;
    }
    __syncthreads();

    // band: thread = (t_local, kgroup); kgroup handles 7 consecutive k
    {
        const int tl = threadIdx.x & 15;
        const int kg = threadIdx.x >> 4;    // 0..15 (kg 15 idle)
        if (kg < 15) {
            float acc[7] = {0.f, 0.f, 0.f, 0.f, 0.f, 0.f, 0.f};
            for (int dd = 0; dd < D_DIM; ++dd) {
                const float a = xs[tl + PADK][dd];
                #pragma unroll
                for (int j = 0; j < 7; ++j)
                    acc[j] += a * xs[tl + kg * 7 + j][dd];   // row = tl + k
            }
            #pragma unroll
            for (int j = 0; j < 7; ++j) {
                const int k = kg * 7 + j;
                if (k < LOOKUP) band[tl][k] = acc[j];
            }
        }
    }
    __syncthreads();

    // FC: thread = (d, t-half); 8 t per thread
    const int d = threadIdx.x & 127;
    const int g = threadIdx.x >> 7;
    const float bias = fc_b[d];
    float acc[8];
    #pragma unroll
    for (int i = 0; i < 8; ++i) acc[i] = bias;
    for (int k = 0; k < LOOKUP; ++k) {
        const float w = fc_w[k * D_DIM + d];
        #pragma unroll
        for (int i = 0; i < 8; ++i)
            acc[i] += band[g * 8 + i][k] * w;
    }
    float* ob = out + ((long long)b * T_DIM + t0) * D_DIM;
    #pragma unroll
    for (int i = 0; i < 8; ++i)
        ob[(g * 8 + i) * D_DIM + d] = fmaxf(acc[i], 0.f);
}

extern "C" void kernel_launch(void* const* d_in, const int* in_sizes, int n_in,
                              void* d_out, int out_size, void* d_ws, size_t ws_size,
                              hipStream_t stream) {
    const float* x0   = (const float*)d_in[0];
    const float* x1   = (const float*)d_in[1];
    const float* Wp   = (const float*)d_in[2];
    const float* fc_w = (const float*)d_in[3];
    const float* fc_b = (const float*)d_in[4];
    float* out = (float*)d_out;

    float* feats = (float*)d_ws;                        // 2*768*2048 f32 = 50.3 MB
    float* x     = feats + 2 * CT * T_DIM;              // 2*2048*128 f32 = 8.4 MB

    // x0: 2*256*2048 = 524288*2 rows of 49
    mean49_kernel<<<4096, 256, 0, stream>>>(x0, feats, 256 * T_DIM, 0);
    // x1: 2*512*2048 rows of 49
    mean49_kernel<<<8192, 256, 0, stream>>>(x1, feats, 512 * T_DIM, 256);

    proj_norm_kernel<<<dim3(T_DIM / 8, 2), 256, 0, stream>>>(feats, Wp, x);
    band_fc_kernel<<<dim3(T_DIM / 16, 2), 256, 0, stream>>>(x, fc_w, fc_b, out);
}

// Round 2
// 752.614 us; speedup vs baseline: 1.0091x; 1.0091x over previous
//
#include <hip/hip_runtime.h>

#define T_DIM 2048
#define D_DIM 128
#define CT 768
#define LOOKUP 101
#define PADK 50

// ---------------- Kernel 1: spatial mean over 7x7=49, both inputs ----------------
// Blocks [0,4096) cover x0 (2*256*2048 rows); blocks [4096,12288) cover x1.
// Each block: 256 rows of 49 floats. Coalesced float4 loads -> LDS, then each
// thread sums one row (stride 49 odd -> max 2-way bank alias, free).
__global__ __launch_bounds__(256) void mean49_all(const float* __restrict__ x0,
                                                  const float* __restrict__ x1,
                                                  float* __restrict__ feats)
{
    __shared__ float4 ldsV[3136];                // 256*49/4 = 50176 B
    float* lds = (float*)ldsV;

    const float* src;
    long long localRow0;
    int shift, chanOff;
    if (blockIdx.x < 4096) {                     // x0: rowsPerBatch = 256*2048 = 2^19
        src = x0; localRow0 = (long long)blockIdx.x * 256; shift = 19; chanOff = 0;
    } else {                                     // x1: rowsPerBatch = 512*2048 = 2^20
        src = x1; localRow0 = (long long)(blockIdx.x - 4096) * 256; shift = 20; chanOff = 256;
    }
    const float4* src4 = (const float4*)(src + localRow0 * 49);

    #pragma unroll
    for (int i = 0; i < 12; ++i)
        ldsV[i * 256 + threadIdx.x] = src4[i * 256 + threadIdx.x];
    if (threadIdx.x < 64)
        ldsV[12 * 256 + threadIdx.x] = src4[12 * 256 + threadIdx.x];
    __syncthreads();

    float s = 0.f;
    #pragma unroll
    for (int i = 0; i < 49; ++i) s += lds[threadIdx.x * 49 + i];
    s *= (1.0f / 49.0f);

    const long long r = localRow0 + threadIdx.x;          // b*rowsPerBatch + c*T + t
    const int b   = (int)(r >> shift);
    const int rem = (int)(r & ((1LL << shift) - 1));      // c*T + t
    feats[(long long)b * (CT * T_DIM) + (long long)chanOff * T_DIM + rem] = s;
}

// ---------------- Kernel 2: projection + L2 normalize ----------------
// x[b,t,d] = sum_c feats[b,c,t] * Wp[c,d]; then row-normalize over d.
// Block: 256 threads = 128 d-lanes x 2 t-groups; t-tile = 8. 512 blocks -> 2/CU.
__global__ __launch_bounds__(256) void proj_norm_kernel(const float* __restrict__ feats,
                                                        const float* __restrict__ Wp,
                                                        float* __restrict__ x)
{
    __shared__ __align__(16) float fTile[CT * 8];    // 24.6 KB
    __shared__ float xTile[8][D_DIM];                // 4 KB
    __shared__ float norms[8];

    const int b  = blockIdx.y;
    const int t0 = blockIdx.x * 8;
    const float* fb = feats + (long long)b * CT * T_DIM;

    // stage feats[b, :, t0:t0+8] : 768 x 8 floats = 1536 float4
    for (int i = threadIdx.x; i < 1536; i += 256) {
        const int c = i >> 1, q = i & 1;
        *(float4*)(&fTile[c * 8 + q * 4]) = *(const float4*)(fb + c * T_DIM + t0 + q * 4);
    }
    __syncthreads();

    const int d = threadIdx.x & 127;
    const int g = threadIdx.x >> 7;    // which 4-t sub-tile
    float a0 = 0.f, a1 = 0.f, a2 = 0.f, a3 = 0.f;
    #pragma unroll 4
    for (int c = 0; c < CT; ++c) {
        const float w = Wp[c * D_DIM + d];
        const float4 f = *(const float4*)(&fTile[c * 8 + g * 4]);
        a0 += w * f.x; a1 += w * f.y; a2 += w * f.z; a3 += w * f.w;
    }
    xTile[g * 4 + 0][d] = a0;
    xTile[g * 4 + 1][d] = a1;
    xTile[g * 4 + 2][d] = a2;
    xTile[g * 4 + 3][d] = a3;
    __syncthreads();

    // norms: wave w reduces rows 2w, 2w+1
    {
        const int wid  = threadIdx.x >> 6;
        const int lane = threadIdx.x & 63;
        #pragma unroll
        for (int tt = 0; tt < 2; ++tt) {
            const int t = wid * 2 + tt;
            float v = xTile[t][lane];
            v = v * v + xTile[t][lane + 64] * xTile[t][lane + 64];
            #pragma unroll
            for (int off = 32; off > 0; off >>= 1) v += __shfl_down(v, off);
            if (lane == 0) norms[t] = v;
        }
    }
    __syncthreads();

    float* xb = x + ((long long)b * T_DIM + t0) * D_DIM;
    #pragma unroll
    for (int i = 0; i < 4; ++i) {
        const int t = g * 4 + i;
        const float n = sqrtf(norms[t]);
        const float sc = 1.0f / fmaxf(n, 1e-12f);
        xb[t * D_DIM + d] = xTile[t][d] * sc;
    }
}

// ---------------- Kernel 3: banded sims + FC + bias + relu ----------------
// band[b,t,k] = dot(x[b,t,:], x[b,t+k-50,:]) (0 if OOB), k in [0,101)
// out[b,t,j] = relu(sum_k band[b,t,k]*fc_w[k,j] + fc_b[j])
// t-tile = 8: LDS 59 KB -> 2 blocks/CU, grid 512 -> 8 waves/CU for latency hiding.
__global__ __launch_bounds__(256) void band_fc_kernel(const float* __restrict__ x,
                                                      const float* __restrict__ fc_w,
                                                      const float* __restrict__ fc_b,
                                                      float* __restrict__ out)
{
    __shared__ float xs[108][D_DIM + 1];   // rows t0-50 .. t0+57; +1 pad (55.7 KB)
    __shared__ float band[8][LOOKUP + 3];  // stride 104 (3.3 KB)

    const int b  = blockIdx.y;
    const int t0 = blockIdx.x * 8;
    const float* xb = x + (long long)b * T_DIM * D_DIM;

    // stage 108 rows, zero-fill OOB
    for (int i = threadIdx.x; i < 108 * D_DIM; i += 256) {
        const int r = i >> 7, dd = i & 127;
        const int s = t0 - PADK + r;
        xs[r][dd] = (s >= 0 && s < T_DIM) ? xb[s * D_DIM + dd] : 0.f;
    }
    __syncthreads();

    // band: thread = (t_local, kgroup); kgroup handles 4 consecutive k
    {
        const int tl = threadIdx.x & 7;
        const int kg = threadIdx.x >> 3;    // 0..31; kg<26 active
        if (kg < 26) {
            float acc[4] = {0.f, 0.f, 0.f, 0.f};
            for (int dd = 0; dd < D_DIM; ++dd) {
                const float a = xs[tl + PADK][dd];
                #pragma unroll
                for (int j = 0; j < 4; ++j)
                    acc[j] += a * xs[tl + kg * 4 + j][dd];   // row = tl + k
            }
            #pragma unroll
            for (int j = 0; j < 4; ++j) {
                const int k = kg * 4 + j;
                if (k < LOOKUP) band[tl][k] = acc[j];
            }
        }
    }
    __syncthreads();

    // FC: thread = (d, t-half); 4 t per thread
    const int d = threadIdx.x & 127;
    const int g = threadIdx.x >> 7;
    const float bias = fc_b[d];
    float acc[4];
    #pragma unroll
    for (int i = 0; i < 4; ++i) acc[i] = bias;
    for (int k = 0; k < LOOKUP; ++k) {
        const float w = fc_w[k * D_DIM + d];
        #pragma unroll
        for (int i = 0; i < 4; ++i)
            acc[i] += band[g * 4 + i][k] * w;
    }
    float* ob = out + ((long long)b * T_DIM + t0) * D_DIM;
    #pragma unroll
    for (int i = 0; i < 4; ++i)
        ob[(g * 4 + i) * D_DIM + d] = fmaxf(acc[i], 0.f);
}

extern "C" void kernel_launch(void* const* d_in, const int* in_sizes, int n_in,
                              void* d_out, int out_size, void* d_ws, size_t ws_size,
                              hipStream_t stream) {
    const float* x0   = (const float*)d_in[0];
    const float* x1   = (const float*)d_in[1];
    const float* Wp   = (const float*)d_in[2];
    const float* fc_w = (const float*)d_in[3];
    const float* fc_b = (const float*)d_in[4];
    float* out = (float*)d_out;

    float* feats = (float*)d_ws;                        // 2*768*2048 f32 = 12.6 MB
    float* x     = feats + 2 * CT * T_DIM;              // 2*2048*128 f32 = 2.1 MB

    mean49_all<<<12288, 256, 0, stream>>>(x0, x1, feats);
    proj_norm_kernel<<<dim3(T_DIM / 8, 2), 256, 0, stream>>>(feats, Wp, x);
    band_fc_kernel<<<dim3(T_DIM / 8, 2), 256, 0, stream>>>(x, fc_w, fc_b, out);
}